// Round 2
// baseline (3786.618 us; speedup 1.0000x reference)
//
#include <hip/hip_runtime.h>

// Emulate numpy f32 per-op rounding exactly: no implicit mul+add fusion.
#pragma clang fp contract(off)

typedef unsigned short u16;
typedef unsigned int u32;
typedef unsigned long long u64;

#define BB 512
#define CC 128
#define TT 500
#define NN 512
#define T_TILE 32
#define LSZ 576                        // list capacity: 512 real + 64 pads

#define TBL_BYTES 1050624ull          // 513*512*4
#define CHUNK_ROW_BYTES 1048576ull    // 512*512*4 per timestep
#define ST_ARR_BYTES 1048576ull       // 512*512*4 per state array
#define PAD_OFF (512u << 11)          // byte offset of the all-zero row

// ---------------- prep kernel ----------------
// Transposed weights with a 513th all-zero row used as the padding target so
// sparse loops run in groups of 8 branch-free (adding 0.0f is exact).
__global__ void prep_weights(const float* __restrict__ W2, const float* __restrict__ Wr2,
                             float* __restrict__ Wr2T, float* __restrict__ W2T) {
  int i = blockIdx.x * blockDim.x + threadIdx.x;
  if (i < 513 * 512) {
    int k = i >> 9, n = i & 511;
    Wr2T[i] = (k < NN) ? Wr2[n * NN + k] : 0.0f;
    W2T[i]  = (k < NN) ? W2[n * NN + k] : 0.0f;
  }
}

// ---------------- i1ff GEMM (chunked): i1ff[b][tl][n] = chain_c x[b][c][t]*W1[n][c] ----
// Bit-exact: each output is ONE ascending-c fmaf chain starting at 0.
__global__ void __launch_bounds__(128, 2)
gemm_i1ff(const float* __restrict__ x, const float* __restrict__ W1,
          float* __restrict__ i1ff, int tBeg, int tLen) {
  const int b = blockIdx.x;
  const int tl0 = blockIdx.y * T_TILE;   // chunk-local t of tile start
  const int tid = threadIdx.x;

  __shared__ float xs[CC * T_TILE];      // [c][j], 16 KB
  __shared__ float W1L[NN * 9];          // [n][cc], padded pitch 9 (odd -> conflict-free), 18 KB

  // stage x tile: consecutive threads -> consecutive t (coalesced)
  for (int i = tid; i < CC * T_TILE; i += 128) {
    int c = i >> 5, j = i & 31;
    int tl = tl0 + j;
    xs[c * T_TILE + j] = (tl < tLen) ? x[(b * CC + c) * TT + (tBeg + tl)] : 0.0f;
  }

  float acc[4][T_TILE];
#pragma unroll
  for (int r = 0; r < 4; ++r)
#pragma unroll
    for (int j = 0; j < T_TILE; ++j) acc[r][j] = 0.0f;

  for (int cp = 0; cp < CC / 8; ++cp) {
    __syncthreads();  // guards xs stores (cp==0) and previous-panel reads
    for (int i = tid; i < NN * 8; i += 128) {
      int nn = i >> 3, cc = i & 7;
      W1L[nn * 9 + cc] = W1[nn * CC + cp * 8 + cc];
    }
    __syncthreads();
#pragma unroll
    for (int cc = 0; cc < 8; ++cc) {
      const int c = cp * 8 + cc;
      float w0 = W1L[(tid + 0)   * 9 + cc];
      float w1 = W1L[(tid + 128) * 9 + cc];
      float w2 = W1L[(tid + 256) * 9 + cc];
      float w3 = W1L[(tid + 384) * 9 + cc];
#pragma unroll
      for (int j = 0; j < T_TILE; ++j) {
        float xv = xs[c * T_TILE + j];   // broadcast (conflict-free)
        acc[0][j] = __builtin_fmaf(xv, w0, acc[0][j]);
        acc[1][j] = __builtin_fmaf(xv, w1, acc[1][j]);
        acc[2][j] = __builtin_fmaf(xv, w2, acc[2][j]);
        acc[3][j] = __builtin_fmaf(xv, w3, acc[3][j]);
      }
    }
  }

#pragma unroll
  for (int j = 0; j < T_TILE; ++j) {
    int tl = tl0 + j;
    if (tl < tLen) {
      float* o = i1ff + ((size_t)b * tLen + tl) * NN;
      o[tid + 0]   = acc[0][j];
      o[tid + 128] = acc[1][j];
      o[tid + 256] = acc[2][j];
      o[tid + 384] = acc[3][j];
    }
  }
}

// ---------------- sparse row-sum (pre-scaled u32 byte offsets, bit-exact order) ----
// Lists are padded with >=64 zero-row entries, so the first PRE*8 elements are
// ALWAYS safe to load unconditionally (adding 0.0f is exact).  The asm fences
// force the compiler to keep all PRE*8 loads issued BEFORE the serial f32 sum
// chain starts (without them it fuses load+sum per group -> one L2 latency per
// group, ~8x serialization; evidenced by VGPR_Count=40 in the previous build).
#define KEEP8(p) asm volatile("" : "+v"((p)[0]), "+v"((p)[1]), "+v"((p)[2]), \
                                   "+v"((p)[3]), "+v"((p)[4]), "+v"((p)[5]), \
                                   "+v"((p)[6]), "+v"((p)[7]))

template <int PRE>
__device__ __forceinline__ float sparse_sum_pre(const float* __restrict__ mat,
                                                const u32* list, int cnt, u32 n4) {
  if (cnt <= 0) return 0.0f;
  const char* base = (const char*)mat;
  float buf[PRE * 8];
#pragma unroll
  for (int g = 0; g < PRE; ++g) {
    uint4 qa = *(const uint4*)(list + g * 8);
    uint4 qb = *(const uint4*)(list + g * 8 + 4);
    buf[g * 8 + 0] = *(const float*)(base + (qa.x + n4));
    buf[g * 8 + 1] = *(const float*)(base + (qa.y + n4));
    buf[g * 8 + 2] = *(const float*)(base + (qa.z + n4));
    buf[g * 8 + 3] = *(const float*)(base + (qa.w + n4));
    buf[g * 8 + 4] = *(const float*)(base + (qb.x + n4));
    buf[g * 8 + 5] = *(const float*)(base + (qb.y + n4));
    buf[g * 8 + 6] = *(const float*)(base + (qb.z + n4));
    buf[g * 8 + 7] = *(const float*)(base + (qb.w + n4));
  }
  asm volatile("" ::: "memory");   // loads may not sink past this point
#pragma unroll
  for (int g = 0; g < PRE; ++g) KEEP8(buf + g * 8);  // sums may not start before
  float s = 0.0f;
#pragma unroll
  for (int g = 0; g < PRE; ++g) {
#pragma unroll
    for (int j = 0; j < 8; ++j) s += buf[g * 8 + j];
  }
  for (int i = PRE * 8; i < cnt; i += 8) {  // rare tail (cnt > PRE*8)
    uint4 qa = *(const uint4*)(list + i);
    uint4 qb = *(const uint4*)(list + i + 4);
    float f0 = *(const float*)(base + (qa.x + n4));
    float f1 = *(const float*)(base + (qa.y + n4));
    float f2 = *(const float*)(base + (qa.z + n4));
    float f3 = *(const float*)(base + (qa.w + n4));
    float f4 = *(const float*)(base + (qb.x + n4));
    float f5 = *(const float*)(base + (qb.y + n4));
    float f6 = *(const float*)(base + (qb.z + n4));
    float f7 = *(const float*)(base + (qb.w + n4));
    s += f0; s += f1; s += f2; s += f3;
    s += f4; s += f5; s += f6; s += f7;
  }
  return s;
}

// position via v_mbcnt (2 VALU); word totals via readfirstlane -> s_bcnt1 (SALU).
// Writes 64 pad entries so unconditional PRE<=8 group loads are always in-bounds.
__device__ __forceinline__ void build_list(const u64* words, int mybit, int wave,
                                           u32 nOff, int n, u32* slot, int* cnt) {
  int tot = 0, base = 0;
#pragma unroll
  for (int j = 0; j < 8; ++j) {
    u64 w = words[j];
    u32 lo = __builtin_amdgcn_readfirstlane((u32)w);
    u32 hi = __builtin_amdgcn_readfirstlane((u32)(w >> 32));
    int pj = __popc(lo) + __popc(hi);
    if (j < wave) base += pj;
    tot += pj;
  }
  if (tot) {
    if (mybit) {
      u64 w = words[wave];
      int below = __builtin_amdgcn_mbcnt_hi((u32)(w >> 32),
                    __builtin_amdgcn_mbcnt_lo((u32)w, 0u));
      slot[base + below] = nOff;
    }
    if (n < 64) slot[tot + n] = PAD_OFF;  // 64 pads -> zero row
  }
  if (n == 0) *cnt = tot;
}

// ---------------- chunked recurrent kernel ----------------
__global__ void __launch_bounds__(512, 4)
recur2(const float* __restrict__ i1ff, const float* __restrict__ Wr2T,
       const float* __restrict__ W2T, const float* __restrict__ W4,
       const float* __restrict__ b1, const float* __restrict__ b2,
       const float* __restrict__ br2, const float* __restrict__ b4,
       const float* __restrict__ Vth1, const float* __restrict__ tau1,
       const float* __restrict__ Vth2, const float* __restrict__ tau2,
       const float* __restrict__ tau_out, float* __restrict__ out,
       float* __restrict__ stM1, float* __restrict__ stM2,
       u32* __restrict__ stSC1, u32* __restrict__ stSC2,
       u64* __restrict__ stW, float* __restrict__ stMemo,
       int tBeg, int tLen, int isFirst, int isLast) {
  const int n = threadIdx.x, b = blockIdx.x;
  const int lane = n & 63, wave = n >> 6;
  const u32 n4 = (u32)(n << 2);
  const u32 nOff = (u32)(n << 11);

  __shared__ u64 wordsA[8], wordsB[8];
  __shared__ __align__(16) u32 listA[2][LSZ];
  __shared__ __align__(16) u32 listB[2][LSZ];
  __shared__ int cA[2], cB[2];

  float mem1, mem2;
  int sc1, sc2;
  float memo0 = 0.0f, memo1 = 0.0f;
  if (isFirst) {
    mem1 = 0.0f; mem2 = 0.0f; sc1 = 0; sc2 = 0;
    if (n < 8) wordsA[n] = 0ull;
    else if (n < 16) wordsB[n - 8] = 0ull;
  } else {
    mem1 = stM1[b * NN + n]; mem2 = stM2[b * NN + n];
    sc1 = (int)stSC1[b * NN + n]; sc2 = (int)stSC2[b * NN + n];
    if (n < 8) wordsA[n] = stW[b * 16 + n];
    else if (n < 16) wordsB[n - 8] = stW[b * 16 + n];
    if (n == 0) { memo0 = stMemo[b * 2]; memo1 = stMemo[b * 2 + 1]; }
  }
  __syncthreads();
  int sp1 = (int)((wordsA[wave] >> lane) & 1ull);
  int sp2 = (int)((wordsB[wave] >> lane) & 1ull);
  // initial lists into parity slot 0 (tBeg is always even)
  build_list(wordsA, sp1, wave, nOff, n, listA[0], &cA[0]);
  build_list(wordsB, sp2, wave, nOff, n, listB[0], &cB[0]);
  // first in-loop B0 orders these before use

  const float b1v = b1[n], b2v = b2[n], br2v = br2[n];
  const float t1 = tau1[n], t2 = tau2[n];
  const float v1 = Vth1[n], v2 = Vth2[n];
  const float to0 = tau_out[0], to1 = tau_out[1];
  const float b40 = b4[0], b41 = b4[1];

  const float* ffp = i1ff + (size_t)b * tLen * NN + n;
  float ffcur = ffp[0];

  for (int t = tBeg; t < tBeg + tLen; ++t) {
    const int tt = t - tBeg;
    const int pp = t & 1, qq = pp ^ 1;
    const int ttn = (tt + 1 < tLen) ? tt + 1 : tt;
    float ffnext = ffp[(size_t)ttn * NN];   // issued pre-barrier, used next iter
    __syncthreads();  // B0

    // ---- layer 1: i1 = (x@W1^T + b1) + (sp1@Wr2^T + br2) ----
    float r1 = sparse_sum_pre<8>(Wr2T, listA[pp], cA[pp], n4);
    float u1 = ffcur + b1v;
    float w1s = r1 + br2v;
    float i1 = u1 + w1s;
    float a1m = t1 * mem1;
    a1m = sp1 ? 0.0f : a1m;
    float m1 = a1m + i1;
    mem1 = m1;
    const int s1 = (m1 - v1) > 0.0f ? 1 : 0;
    u64 ba = __ballot(s1 != 0);
    if (lane == 0) wordsA[wave] = ba;
    __syncthreads();  // B1

    build_list(wordsA, s1, wave, nOff, n, listA[qq], &cA[qq]);
    __syncthreads();  // B1b

    // ---- layer 2: i2 = (s1@W2^T + b2) + (sp2@Wr2^T + br2) ----
    float ff = sparse_sum_pre<8>(W2T, listA[qq], cA[qq], n4);
    float u2 = ff + b2v;
    float r2 = sparse_sum_pre<8>(Wr2T, listB[pp], cB[pp], n4);
    float w2s = r2 + br2v;
    float i2 = u2 + w2s;
    float a2m = t2 * mem2;
    a2m = sp2 ? 0.0f : a2m;
    float m2 = a2m + i2;
    mem2 = m2;
    const int s2 = (m2 - v2) > 0.0f ? 1 : 0;
    u64 bb = __ballot(s2 != 0);
    if (lane == 0) wordsB[wave] = bb;
    sp1 = s1; sp2 = s2; sc1 += s1; sc2 += s2;
    ffcur = ffnext;
    __syncthreads();  // B2

    build_list(wordsB, s2, wave, nOff, n, listB[qq], &cB[qq]);

    // ---- readout: memo = (tau_out*memo) + ((s2@W4^T) + b4) ----
    if (n == 0) {
      float a0 = 0.0f, a1 = 0.0f;  // ascending-k f32 chains (s2 ~never fires)
#pragma unroll
      for (int w = 0; w < 8; ++w) {
        u64 m = wordsB[w];
        while (m) {
          int k = (w << 6) + __builtin_ctzll(m);
          m &= m - 1ull;
          a0 += W4[k];
          a1 += W4[NN + k];
        }
      }
      float z0 = to0 * memo0;
      float z1 = to1 * memo1;
      memo0 = z0 + (a0 + b40);
      memo1 = z1 + (a1 + b41);
      out[(b * 2 + 0) * TT + t] = memo0;
      out[(b * 2 + 1) * TT + t] = memo1;
    }
  }

  if (isLast) {
    out[BB * 2 * TT + b * NN + n]           = (float)sc1 / 500.0f;
    out[BB * 2 * TT + BB * NN + b * NN + n] = (float)sc2 / 500.0f;
  } else {
    __syncthreads();
    stM1[b * NN + n] = mem1; stM2[b * NN + n] = mem2;
    stSC1[b * NN + n] = (u32)sc1; stSC2[b * NN + n] = (u32)sc2;
    if (n < 8) stW[b * 16 + n] = wordsA[n];
    else if (n < 16) stW[b * 16 + n] = wordsB[n - 8];
    if (n == 0) { stMemo[b * 2] = memo0; stMemo[b * 2 + 1] = memo1; }
  }
}

// ---------------- fallback monolithic kernel (tiny ws): no-spill GEMV ----------------
__global__ void __launch_bounds__(512) __attribute__((amdgpu_waves_per_eu(2, 2)))
recur_fb(const float* __restrict__ x, const float* __restrict__ W1,
         const float* __restrict__ Wr2T, const float* __restrict__ W2T,
         const float* __restrict__ W4,
         const float* __restrict__ b1, const float* __restrict__ b2,
         const float* __restrict__ br2, const float* __restrict__ b4,
         const float* __restrict__ Vth1, const float* __restrict__ tau1,
         const float* __restrict__ Vth2, const float* __restrict__ tau2,
         const float* __restrict__ tau_out, float* __restrict__ out) {
  const int n = threadIdx.x, b = blockIdx.x;
  const int lane = n & 63, wave = n >> 6;
  const u32 n4 = (u32)(n << 2);
  const u32 nOff = (u32)(n << 11);

  __shared__ float xs[CC];
  __shared__ u64 wordsA[8], wordsB[8];
  __shared__ __align__(16) u32 listA[2][LSZ];
  __shared__ __align__(16) u32 listB[2][LSZ];
  __shared__ int cA[2], cB[2];

  float w1r[CC];  // fits: waves_per_eu(2,2) -> 256-VGPR budget, no spill
  {
    const float4* wp = (const float4*)(W1 + n * CC);
#pragma unroll
    for (int i = 0; i < CC / 4; ++i) {
      float4 q = wp[i];
      w1r[i * 4 + 0] = q.x; w1r[i * 4 + 1] = q.y;
      w1r[i * 4 + 2] = q.z; w1r[i * 4 + 3] = q.w;
    }
  }

  float mem1 = 0.0f, mem2 = 0.0f;
  const float b1v = b1[n], b2v = b2[n], br2v = br2[n];
  const float t1 = tau1[n], t2 = tau2[n];
  const float v1 = Vth1[n], v2 = Vth2[n];
  const float to0 = tau_out[0], to1 = tau_out[1];
  const float b40 = b4[0], b41 = b4[1];
  int sp1 = 0, sp2 = 0, sc1 = 0, sc2 = 0;
  float memo0 = 0.0f, memo1 = 0.0f;

  if (n == 0) { cA[0] = 0; cB[0] = 0; }

  for (int t = 0; t < TT; ++t) {
    const int pp = t & 1, qq = pp ^ 1;
    if (n < CC) xs[n] = x[(b * CC + n) * TT + t];
    __syncthreads();

    float acc = 0.0f;
#pragma unroll
    for (int c = 0; c < CC; ++c) acc = __builtin_fmaf(xs[c], w1r[c], acc);
    float u1 = acc + b1v;
    float r1 = sparse_sum_pre<6>(Wr2T, listA[pp], cA[pp], n4);
    float w1s = r1 + br2v;
    float i1 = u1 + w1s;
    float a1m = t1 * mem1;
    a1m = sp1 ? 0.0f : a1m;
    float m1 = a1m + i1;
    mem1 = m1;
    const int s1 = (m1 - v1) > 0.0f ? 1 : 0;
    u64 ba = __ballot(s1 != 0);
    if (lane == 0) wordsA[wave] = ba;
    __syncthreads();

    build_list(wordsA, s1, wave, nOff, n, listA[qq], &cA[qq]);
    __syncthreads();

    float ff = sparse_sum_pre<6>(W2T, listA[qq], cA[qq], n4);
    float u2 = ff + b2v;
    float r2 = sparse_sum_pre<6>(Wr2T, listB[pp], cB[pp], n4);
    float w2s = r2 + br2v;
    float i2 = u2 + w2s;
    float a2m = t2 * mem2;
    a2m = sp2 ? 0.0f : a2m;
    float m2 = a2m + i2;
    mem2 = m2;
    const int s2 = (m2 - v2) > 0.0f ? 1 : 0;
    u64 bb = __ballot(s2 != 0);
    if (lane == 0) wordsB[wave] = bb;
    sp1 = s1; sp2 = s2; sc1 += s1; sc2 += s2;
    __syncthreads();

    build_list(wordsB, s2, wave, nOff, n, listB[qq], &cB[qq]);

    if (n == 0) {
      float a0 = 0.0f, a1 = 0.0f;
#pragma unroll
      for (int w = 0; w < 8; ++w) {
        u64 m = wordsB[w];
        while (m) {
          int k = (w << 6) + __builtin_ctzll(m);
          m &= m - 1ull;
          a0 += W4[k];
          a1 += W4[NN + k];
        }
      }
      float z0 = to0 * memo0;
      float z1 = to1 * memo1;
      memo0 = z0 + (a0 + b40);
      memo1 = z1 + (a1 + b41);
      out[(b * 2 + 0) * TT + t] = memo0;
      out[(b * 2 + 1) * TT + t] = memo1;
    }
  }

  out[BB * 2 * TT + b * NN + n]           = (float)sc1 / 500.0f;
  out[BB * 2 * TT + BB * NN + b * NN + n] = (float)sc2 / 500.0f;
}

// ---------------- launcher ----------------
extern "C" void kernel_launch(void* const* d_in, const int* in_sizes, int n_in,
                              void* d_out, int out_size, void* d_ws, size_t ws_size,
                              hipStream_t stream) {
  (void)in_sizes; (void)n_in; (void)out_size;
  const float* x    = (const float*)d_in[0];
  const float* W1   = (const float*)d_in[1];
  const float* b1   = (const float*)d_in[2];
  const float* W2   = (const float*)d_in[3];
  const float* b2   = (const float*)d_in[4];
  const float* Wr2  = (const float*)d_in[5];
  const float* br2  = (const float*)d_in[6];
  // d_in[7..10] = W3,b3,Wr3,br3: dead code w.r.t. outputs — skipped
  const float* W4   = (const float*)d_in[11];
  const float* b4   = (const float*)d_in[12];
  const float* Vth1 = (const float*)d_in[13];
  const float* tau1 = (const float*)d_in[14];
  const float* Vth2 = (const float*)d_in[15];
  const float* tau2 = (const float*)d_in[16];
  const float* tau_out = (const float*)d_in[19];

  char* ws = (char*)d_ws;

  // aux: 2 weight tables + 4 state arrays + ballot words + memo
  const size_t aux = 2 * TBL_BYTES + 4 * ST_ARR_BYTES + 512ull * 16 * 8 + 512ull * 2 * 4;

  int chunkT = 0;
  if (ws_size > aux) {
    long long ct = (long long)((ws_size - aux) / CHUNK_ROW_BYTES);
    if (ct > TT) ct = TT;
    ct &= ~1LL;  // even start for every chunk (list parity)
    if (ct >= 16) chunkT = (int)ct;
  }

  if (chunkT >= 16) {
    char* p = ws;
    float* i1ff = (float*)p;  p += (size_t)chunkT * CHUNK_ROW_BYTES;
    float* Wr2T = (float*)p;  p += TBL_BYTES;
    float* W2T  = (float*)p;  p += TBL_BYTES;
    float* stM1 = (float*)p;  p += ST_ARR_BYTES;
    float* stM2 = (float*)p;  p += ST_ARR_BYTES;
    u32* stSC1  = (u32*)p;    p += ST_ARR_BYTES;
    u32* stSC2  = (u32*)p;    p += ST_ARR_BYTES;
    u64* stW    = (u64*)p;    p += 512ull * 16 * 8;
    float* stMemo = (float*)p;

    hipLaunchKernelGGL(prep_weights, dim3((513 * 512 + 255) / 256), dim3(256), 0, stream,
                       W2, Wr2, Wr2T, W2T);
    for (int t0 = 0; t0 < TT; t0 += chunkT) {
      int len = (TT - t0 < chunkT) ? (TT - t0) : chunkT;
      hipLaunchKernelGGL(gemm_i1ff, dim3(BB, (len + T_TILE - 1) / T_TILE), dim3(128), 0,
                         stream, x, W1, i1ff, t0, len);
      hipLaunchKernelGGL(recur2, dim3(BB), dim3(512), 0, stream,
                         i1ff, Wr2T, W2T, W4, b1, b2, br2, b4,
                         Vth1, tau1, Vth2, tau2, tau_out, (float*)d_out,
                         stM1, stM2, stSC1, stSC2, stW, stMemo,
                         t0, len, (t0 == 0) ? 1 : 0, (t0 + len == TT) ? 1 : 0);
    }
  } else {
    float* Wr2T = (float*)ws;
    float* W2T  = (float*)(ws + TBL_BYTES);
    hipLaunchKernelGGL(prep_weights, dim3((513 * 512 + 255) / 256), dim3(256), 0, stream,
                       W2, Wr2, Wr2T, W2T);
    hipLaunchKernelGGL(recur_fb, dim3(BB), dim3(512), 0, stream,
                       x, W1, Wr2T, W2T, W4, b1, b2, br2, b4,
                       Vth1, tau1, Vth2, tau2, tau_out, (float*)d_out);
  }
}

// Round 3
// 2967.053 us; speedup vs baseline: 1.2762x; 1.2762x over previous
//
#include <hip/hip_runtime.h>

// Emulate numpy f32 per-op rounding exactly: no implicit mul+add fusion.
#pragma clang fp contract(off)

typedef unsigned short u16;
typedef unsigned int u32;
typedef unsigned long long u64;

#define BB 512
#define CC 128
#define TT 500
#define NN 512
#define T_TILE 32
#define LSZ 576                        // list capacity: 512 real + 64 pads

#define TBL_BYTES 1050624ull          // 513*512*4
#define CHUNK_ROW_BYTES 1048576ull    // 512*512*4 per timestep
#define ST_ARR_BYTES 1048576ull       // 512*512*4 per state array
#define PAD_OFF (512u << 11)          // byte offset of the all-zero row

// ---------------- prep kernel ----------------
// Transposed weights with a 513th all-zero row used as the padding target so
// sparse loops run in groups of 32 branch-free (adding 0.0f is exact).
__global__ void prep_weights(const float* __restrict__ W2, const float* __restrict__ Wr2,
                             float* __restrict__ Wr2T, float* __restrict__ W2T) {
  int i = blockIdx.x * blockDim.x + threadIdx.x;
  if (i < 513 * 512) {
    int k = i >> 9, n = i & 511;
    Wr2T[i] = (k < NN) ? Wr2[n * NN + k] : 0.0f;
    W2T[i]  = (k < NN) ? W2[n * NN + k] : 0.0f;
  }
}

// ---------------- i1ff GEMM (chunked): i1ff[b][tl][n] = chain_c x[b][c][t]*W1[n][c] ----
// Bit-exact: each output is ONE ascending-c fmaf chain starting at 0.
// xs read as float4 (ds_read_b128 broadcast) -> 4x fewer LDS issues; per-acc
// fma order unchanged (one fma per c, c ascending).
__global__ void __launch_bounds__(128, 2)
gemm_i1ff(const float* __restrict__ x, const float* __restrict__ W1,
          float* __restrict__ i1ff, int tBeg, int tLen) {
  const int b = blockIdx.x;
  const int tl0 = blockIdx.y * T_TILE;   // chunk-local t of tile start
  const int tid = threadIdx.x;

  __shared__ __align__(16) float xs[CC * T_TILE];  // [c][j], 16 KB
  __shared__ float W1L[NN * 9];          // [n][cc], padded pitch 9 (odd -> conflict-free), 18 KB

  // stage x tile: consecutive threads -> consecutive t (coalesced)
  for (int i = tid; i < CC * T_TILE; i += 128) {
    int c = i >> 5, j = i & 31;
    int tl = tl0 + j;
    xs[c * T_TILE + j] = (tl < tLen) ? x[(b * CC + c) * TT + (tBeg + tl)] : 0.0f;
  }

  float acc[4][T_TILE];
#pragma unroll
  for (int r = 0; r < 4; ++r)
#pragma unroll
    for (int j = 0; j < T_TILE; ++j) acc[r][j] = 0.0f;

  for (int cp = 0; cp < CC / 8; ++cp) {
    __syncthreads();  // guards xs stores (cp==0) and previous-panel reads
    for (int i = tid; i < NN * 8; i += 128) {
      int nn = i >> 3, cc = i & 7;
      W1L[nn * 9 + cc] = W1[nn * CC + cp * 8 + cc];
    }
    __syncthreads();
#pragma unroll
    for (int cc = 0; cc < 8; ++cc) {
      const int c = cp * 8 + cc;
      float w0 = W1L[(tid + 0)   * 9 + cc];
      float w1 = W1L[(tid + 128) * 9 + cc];
      float w2 = W1L[(tid + 256) * 9 + cc];
      float w3 = W1L[(tid + 384) * 9 + cc];
      const float4* xp = (const float4*)(xs + c * T_TILE);
#pragma unroll
      for (int j4 = 0; j4 < T_TILE / 4; ++j4) {
        float4 xq = xp[j4];              // 16B broadcast, conflict-free
        const int j = j4 * 4;
        acc[0][j + 0] = __builtin_fmaf(xq.x, w0, acc[0][j + 0]);
        acc[1][j + 0] = __builtin_fmaf(xq.x, w1, acc[1][j + 0]);
        acc[2][j + 0] = __builtin_fmaf(xq.x, w2, acc[2][j + 0]);
        acc[3][j + 0] = __builtin_fmaf(xq.x, w3, acc[3][j + 0]);
        acc[0][j + 1] = __builtin_fmaf(xq.y, w0, acc[0][j + 1]);
        acc[1][j + 1] = __builtin_fmaf(xq.y, w1, acc[1][j + 1]);
        acc[2][j + 1] = __builtin_fmaf(xq.y, w2, acc[2][j + 1]);
        acc[3][j + 1] = __builtin_fmaf(xq.y, w3, acc[3][j + 1]);
        acc[0][j + 2] = __builtin_fmaf(xq.z, w0, acc[0][j + 2]);
        acc[1][j + 2] = __builtin_fmaf(xq.z, w1, acc[1][j + 2]);
        acc[2][j + 2] = __builtin_fmaf(xq.z, w2, acc[2][j + 2]);
        acc[3][j + 2] = __builtin_fmaf(xq.z, w3, acc[3][j + 2]);
        acc[0][j + 3] = __builtin_fmaf(xq.w, w0, acc[0][j + 3]);
        acc[1][j + 3] = __builtin_fmaf(xq.w, w1, acc[1][j + 3]);
        acc[2][j + 3] = __builtin_fmaf(xq.w, w2, acc[2][j + 3]);
        acc[3][j + 3] = __builtin_fmaf(xq.w, w3, acc[3][j + 3]);
      }
    }
  }

#pragma unroll
  for (int j = 0; j < T_TILE; ++j) {
    int tl = tl0 + j;
    if (tl < tLen) {
      float* o = i1ff + ((size_t)b * tLen + tl) * NN;
      o[tid + 0]   = acc[0][j];
      o[tid + 128] = acc[1][j];
      o[tid + 256] = acc[2][j];
      o[tid + 384] = acc[3][j];
    }
  }
}

// ---------------- sparse row-sum (pre-scaled u32 byte offsets, bit-exact order) ----
// 32-deep MLP per group via NAMED scalars (no array -> no scratch alloca; the
// round-2 buf[64] version was spilled to scratch: VGPR=48 + 128 extra memory
// ops/gather).  The memory-clobber asm keeps all 32 global loads issued before
// the KEEP4 value-barriers; the serial f32 chain then pays ~one L2 latency per
// 32 elements instead of per 8.  Lists carry >=32 pad entries (zero row), so
// the group overhang adds exact 0.0f.
#define KEEP4(a, b, c, d) asm volatile("" : "+v"(a), "+v"(b), "+v"(c), "+v"(d))

__device__ __forceinline__ float sparse_sum32(const float* __restrict__ mat,
                                              const u32* list, int cnt, u32 n4) {
  const char* base = (const char*)mat;
  float s = 0.0f;
  for (int i = 0; i < cnt; i += 32) {   // wave-uniform trip count (cnt from LDS)
    const u32* lp = list + i;
    uint4 q0 = *(const uint4*)(lp + 0);
    uint4 q1 = *(const uint4*)(lp + 4);
    uint4 q2 = *(const uint4*)(lp + 8);
    uint4 q3 = *(const uint4*)(lp + 12);
    uint4 q4 = *(const uint4*)(lp + 16);
    uint4 q5 = *(const uint4*)(lp + 20);
    uint4 q6 = *(const uint4*)(lp + 24);
    uint4 q7 = *(const uint4*)(lp + 28);
    float f00 = *(const float*)(base + (q0.x + n4));
    float f01 = *(const float*)(base + (q0.y + n4));
    float f02 = *(const float*)(base + (q0.z + n4));
    float f03 = *(const float*)(base + (q0.w + n4));
    float f04 = *(const float*)(base + (q1.x + n4));
    float f05 = *(const float*)(base + (q1.y + n4));
    float f06 = *(const float*)(base + (q1.z + n4));
    float f07 = *(const float*)(base + (q1.w + n4));
    float f08 = *(const float*)(base + (q2.x + n4));
    float f09 = *(const float*)(base + (q2.y + n4));
    float f10 = *(const float*)(base + (q2.z + n4));
    float f11 = *(const float*)(base + (q2.w + n4));
    float f12 = *(const float*)(base + (q3.x + n4));
    float f13 = *(const float*)(base + (q3.y + n4));
    float f14 = *(const float*)(base + (q3.z + n4));
    float f15 = *(const float*)(base + (q3.w + n4));
    float f16 = *(const float*)(base + (q4.x + n4));
    float f17 = *(const float*)(base + (q4.y + n4));
    float f18 = *(const float*)(base + (q4.z + n4));
    float f19 = *(const float*)(base + (q4.w + n4));
    float f20 = *(const float*)(base + (q5.x + n4));
    float f21 = *(const float*)(base + (q5.y + n4));
    float f22 = *(const float*)(base + (q5.z + n4));
    float f23 = *(const float*)(base + (q5.w + n4));
    float f24 = *(const float*)(base + (q6.x + n4));
    float f25 = *(const float*)(base + (q6.y + n4));
    float f26 = *(const float*)(base + (q6.z + n4));
    float f27 = *(const float*)(base + (q6.w + n4));
    float f28 = *(const float*)(base + (q7.x + n4));
    float f29 = *(const float*)(base + (q7.y + n4));
    float f30 = *(const float*)(base + (q7.z + n4));
    float f31 = *(const float*)(base + (q7.w + n4));
    asm volatile("" ::: "memory");  // all 32 loads issued before this point
    KEEP4(f00, f01, f02, f03);
    KEEP4(f04, f05, f06, f07);
    KEEP4(f08, f09, f10, f11);
    KEEP4(f12, f13, f14, f15);
    KEEP4(f16, f17, f18, f19);
    KEEP4(f20, f21, f22, f23);
    KEEP4(f24, f25, f26, f27);
    KEEP4(f28, f29, f30, f31);
    s += f00; s += f01; s += f02; s += f03;
    s += f04; s += f05; s += f06; s += f07;
    s += f08; s += f09; s += f10; s += f11;
    s += f12; s += f13; s += f14; s += f15;
    s += f16; s += f17; s += f18; s += f19;
    s += f20; s += f21; s += f22; s += f23;
    s += f24; s += f25; s += f26; s += f27;
    s += f28; s += f29; s += f30; s += f31;
  }
  return s;
}

// position via v_mbcnt (2 VALU); word totals via readfirstlane -> s_bcnt1 (SALU).
// Writes 64 pad entries so unconditional 32-wide group loads are always covered.
__device__ __forceinline__ void build_list(const u64* words, int mybit, int wave,
                                           u32 nOff, int n, u32* slot, int* cnt) {
  int tot = 0, base = 0;
#pragma unroll
  for (int j = 0; j < 8; ++j) {
    u64 w = words[j];
    u32 lo = __builtin_amdgcn_readfirstlane((u32)w);
    u32 hi = __builtin_amdgcn_readfirstlane((u32)(w >> 32));
    int pj = __popc(lo) + __popc(hi);
    if (j < wave) base += pj;
    tot += pj;
  }
  if (tot) {
    if (mybit) {
      u64 w = words[wave];
      int below = __builtin_amdgcn_mbcnt_hi((u32)(w >> 32),
                    __builtin_amdgcn_mbcnt_lo((u32)w, 0u));
      slot[base + below] = nOff;
    }
    if (n < 64) slot[tot + n] = PAD_OFF;  // pads -> zero row
  }
  if (n == 0) *cnt = tot;
}

// ---------------- chunked recurrent kernel ----------------
__global__ void __launch_bounds__(512, 4)
recur2(const float* __restrict__ i1ff, const float* __restrict__ Wr2T,
       const float* __restrict__ W2T, const float* __restrict__ W4,
       const float* __restrict__ b1, const float* __restrict__ b2,
       const float* __restrict__ br2, const float* __restrict__ b4,
       const float* __restrict__ Vth1, const float* __restrict__ tau1,
       const float* __restrict__ Vth2, const float* __restrict__ tau2,
       const float* __restrict__ tau_out, float* __restrict__ out,
       float* __restrict__ stM1, float* __restrict__ stM2,
       u32* __restrict__ stSC1, u32* __restrict__ stSC2,
       u64* __restrict__ stW, float* __restrict__ stMemo,
       int tBeg, int tLen, int isFirst, int isLast) {
  const int n = threadIdx.x, b = blockIdx.x;
  const int lane = n & 63, wave = n >> 6;
  const u32 n4 = (u32)(n << 2);
  const u32 nOff = (u32)(n << 11);

  __shared__ u64 wordsA[8], wordsB[8];
  __shared__ __align__(16) u32 listA[2][LSZ];
  __shared__ __align__(16) u32 listB[2][LSZ];
  __shared__ int cA[2], cB[2];

  float mem1, mem2;
  int sc1, sc2;
  // readout split: thread 0 owns row 0, thread 64 owns row 1 (parallel serial
  // chains on different waves; each chain's add order identical to before).
  const int ro = n >> 6;
  const bool isRd = (n == 0) || (n == 64);
  float memo = 0.0f;
  if (isFirst) {
    mem1 = 0.0f; mem2 = 0.0f; sc1 = 0; sc2 = 0;
    if (n < 8) wordsA[n] = 0ull;
    else if (n < 16) wordsB[n - 8] = 0ull;
  } else {
    mem1 = stM1[b * NN + n]; mem2 = stM2[b * NN + n];
    sc1 = (int)stSC1[b * NN + n]; sc2 = (int)stSC2[b * NN + n];
    if (n < 8) wordsA[n] = stW[b * 16 + n];
    else if (n < 16) wordsB[n - 8] = stW[b * 16 + n];
    if (isRd) memo = stMemo[b * 2 + ro];
  }
  __syncthreads();
  int sp1 = (int)((wordsA[wave] >> lane) & 1ull);
  int sp2 = (int)((wordsB[wave] >> lane) & 1ull);
  // initial lists into parity slot 0 (tBeg is always even)
  build_list(wordsA, sp1, wave, nOff, n, listA[0], &cA[0]);
  build_list(wordsB, sp2, wave, nOff, n, listB[0], &cB[0]);
  // first in-loop B0 orders these before use

  const float b1v = b1[n], b2v = b2[n], br2v = br2[n];
  const float t1 = tau1[n], t2 = tau2[n];
  const float v1 = Vth1[n], v2 = Vth2[n];
  const float tov = tau_out[ro & 1];
  const float b4v = b4[ro & 1];

  const float* ffp = i1ff + (size_t)b * tLen * NN + n;
  float ffcur = ffp[0];

  for (int t = tBeg; t < tBeg + tLen; ++t) {
    const int tt = t - tBeg;
    const int pp = t & 1, qq = pp ^ 1;
    const int ttn = (tt + 1 < tLen) ? tt + 1 : tt;
    float ffnext = ffp[(size_t)ttn * NN];   // issued pre-barrier, used next iter
    __syncthreads();  // B0

    // ---- layer 1: i1 = (x@W1^T + b1) + (sp1@Wr2^T + br2) ----
    float r1 = sparse_sum32(Wr2T, listA[pp], cA[pp], n4);
    float u1 = ffcur + b1v;
    float w1s = r1 + br2v;
    float i1 = u1 + w1s;
    float a1m = t1 * mem1;
    a1m = sp1 ? 0.0f : a1m;
    float m1 = a1m + i1;
    mem1 = m1;
    const int s1 = (m1 - v1) > 0.0f ? 1 : 0;
    u64 ba = __ballot(s1 != 0);
    if (lane == 0) wordsA[wave] = ba;
    __syncthreads();  // B1

    build_list(wordsA, s1, wave, nOff, n, listA[qq], &cA[qq]);
    __syncthreads();  // B1b

    // ---- layer 2: i2 = (s1@W2^T + b2) + (sp2@Wr2^T + br2) ----
    float ff = sparse_sum32(W2T, listA[qq], cA[qq], n4);
    float u2 = ff + b2v;
    float r2 = sparse_sum32(Wr2T, listB[pp], cB[pp], n4);
    float w2s = r2 + br2v;
    float i2 = u2 + w2s;
    float a2m = t2 * mem2;
    a2m = sp2 ? 0.0f : a2m;
    float m2 = a2m + i2;
    mem2 = m2;
    const int s2 = (m2 - v2) > 0.0f ? 1 : 0;
    u64 bb = __ballot(s2 != 0);
    if (lane == 0) wordsB[wave] = bb;
    sp1 = s1; sp2 = s2; sc1 += s1; sc2 += s2;
    ffcur = ffnext;
    __syncthreads();  // B2

    build_list(wordsB, s2, wave, nOff, n, listB[qq], &cB[qq]);

    // ---- readout: memo = (tau_out*memo) + ((s2@W4^T) + b4) ----
    if (isRd) {
      const float* w4r = W4 + ro * NN;
      float a = 0.0f;  // ascending-k f32 chain (s2 sparse)
#pragma unroll
      for (int w = 0; w < 8; ++w) {
        u64 m = wordsB[w];
        while (m) {
          int k = (w << 6) + __builtin_ctzll(m);
          m &= m - 1ull;
          a += w4r[k];
        }
      }
      float z = tov * memo;
      memo = z + (a + b4v);
      out[(b * 2 + ro) * TT + t] = memo;
    }
  }

  if (isLast) {
    out[BB * 2 * TT + b * NN + n]           = (float)sc1 / 500.0f;
    out[BB * 2 * TT + BB * NN + b * NN + n] = (float)sc2 / 500.0f;
  } else {
    __syncthreads();
    stM1[b * NN + n] = mem1; stM2[b * NN + n] = mem2;
    stSC1[b * NN + n] = (u32)sc1; stSC2[b * NN + n] = (u32)sc2;
    if (n < 8) stW[b * 16 + n] = wordsA[n];
    else if (n < 16) stW[b * 16 + n] = wordsB[n - 8];
    if (isRd) stMemo[b * 2 + ro] = memo;
  }
}

// ---------------- fallback monolithic kernel (tiny ws): no-spill GEMV ----------------
__global__ void __launch_bounds__(512) __attribute__((amdgpu_waves_per_eu(2, 2)))
recur_fb(const float* __restrict__ x, const float* __restrict__ W1,
         const float* __restrict__ Wr2T, const float* __restrict__ W2T,
         const float* __restrict__ W4,
         const float* __restrict__ b1, const float* __restrict__ b2,
         const float* __restrict__ br2, const float* __restrict__ b4,
         const float* __restrict__ Vth1, const float* __restrict__ tau1,
         const float* __restrict__ Vth2, const float* __restrict__ tau2,
         const float* __restrict__ tau_out, float* __restrict__ out) {
  const int n = threadIdx.x, b = blockIdx.x;
  const int lane = n & 63, wave = n >> 6;
  const u32 n4 = (u32)(n << 2);
  const u32 nOff = (u32)(n << 11);

  __shared__ float xs[CC];
  __shared__ u64 wordsA[8], wordsB[8];
  __shared__ __align__(16) u32 listA[2][LSZ];
  __shared__ __align__(16) u32 listB[2][LSZ];
  __shared__ int cA[2], cB[2];

  float w1r[CC];  // fits: waves_per_eu(2,2) -> 256-VGPR budget, no spill
  {
    const float4* wp = (const float4*)(W1 + n * CC);
#pragma unroll
    for (int i = 0; i < CC / 4; ++i) {
      float4 q = wp[i];
      w1r[i * 4 + 0] = q.x; w1r[i * 4 + 1] = q.y;
      w1r[i * 4 + 2] = q.z; w1r[i * 4 + 3] = q.w;
    }
  }

  float mem1 = 0.0f, mem2 = 0.0f;
  const float b1v = b1[n], b2v = b2[n], br2v = br2[n];
  const float t1 = tau1[n], t2 = tau2[n];
  const float v1 = Vth1[n], v2 = Vth2[n];
  const float to0 = tau_out[0], to1 = tau_out[1];
  const float b40 = b4[0], b41 = b4[1];
  int sp1 = 0, sp2 = 0, sc1 = 0, sc2 = 0;
  float memo0 = 0.0f, memo1 = 0.0f;

  if (n == 0) { cA[0] = 0; cB[0] = 0; }

  for (int t = 0; t < TT; ++t) {
    const int pp = t & 1, qq = pp ^ 1;
    if (n < CC) xs[n] = x[(b * CC + n) * TT + t];
    __syncthreads();

    float acc = 0.0f;
#pragma unroll
    for (int c = 0; c < CC; ++c) acc = __builtin_fmaf(xs[c], w1r[c], acc);
    float u1 = acc + b1v;
    float r1 = sparse_sum32(Wr2T, listA[pp], cA[pp], n4);
    float w1s = r1 + br2v;
    float i1 = u1 + w1s;
    float a1m = t1 * mem1;
    a1m = sp1 ? 0.0f : a1m;
    float m1 = a1m + i1;
    mem1 = m1;
    const int s1 = (m1 - v1) > 0.0f ? 1 : 0;
    u64 ba = __ballot(s1 != 0);
    if (lane == 0) wordsA[wave] = ba;
    __syncthreads();

    build_list(wordsA, s1, wave, nOff, n, listA[qq], &cA[qq]);
    __syncthreads();

    float ff = sparse_sum32(W2T, listA[qq], cA[qq], n4);
    float u2 = ff + b2v;
    float r2 = sparse_sum32(Wr2T, listB[pp], cB[pp], n4);
    float w2s = r2 + br2v;
    float i2 = u2 + w2s;
    float a2m = t2 * mem2;
    a2m = sp2 ? 0.0f : a2m;
    float m2 = a2m + i2;
    mem2 = m2;
    const int s2 = (m2 - v2) > 0.0f ? 1 : 0;
    u64 bb = __ballot(s2 != 0);
    if (lane == 0) wordsB[wave] = bb;
    sp1 = s1; sp2 = s2; sc1 += s1; sc2 += s2;
    __syncthreads();

    build_list(wordsB, s2, wave, nOff, n, listB[qq], &cB[qq]);

    if (n == 0) {
      float a0 = 0.0f, a1 = 0.0f;
#pragma unroll
      for (int w = 0; w < 8; ++w) {
        u64 m = wordsB[w];
        while (m) {
          int k = (w << 6) + __builtin_ctzll(m);
          m &= m - 1ull;
          a0 += W4[k];
          a1 += W4[NN + k];
        }
      }
      float z0 = to0 * memo0;
      float z1 = to1 * memo1;
      memo0 = z0 + (a0 + b40);
      memo1 = z1 + (a1 + b41);
      out[(b * 2 + 0) * TT + t] = memo0;
      out[(b * 2 + 1) * TT + t] = memo1;
    }
  }

  out[BB * 2 * TT + b * NN + n]           = (float)sc1 / 500.0f;
  out[BB * 2 * TT + BB * NN + b * NN + n] = (float)sc2 / 500.0f;
}

// ---------------- launcher ----------------
extern "C" void kernel_launch(void* const* d_in, const int* in_sizes, int n_in,
                              void* d_out, int out_size, void* d_ws, size_t ws_size,
                              hipStream_t stream) {
  (void)in_sizes; (void)n_in; (void)out_size;
  const float* x    = (const float*)d_in[0];
  const float* W1   = (const float*)d_in[1];
  const float* b1   = (const float*)d_in[2];
  const float* W2   = (const float*)d_in[3];
  const float* b2   = (const float*)d_in[4];
  const float* Wr2  = (const float*)d_in[5];
  const float* br2  = (const float*)d_in[6];
  // d_in[7..10] = W3,b3,Wr3,br3: dead code w.r.t. outputs — skipped
  const float* W4   = (const float*)d_in[11];
  const float* b4   = (const float*)d_in[12];
  const float* Vth1 = (const float*)d_in[13];
  const float* tau1 = (const float*)d_in[14];
  const float* Vth2 = (const float*)d_in[15];
  const float* tau2 = (const float*)d_in[16];
  const float* tau_out = (const float*)d_in[19];

  char* ws = (char*)d_ws;

  // aux: 2 weight tables + 4 state arrays + ballot words + memo
  const size_t aux = 2 * TBL_BYTES + 4 * ST_ARR_BYTES + 512ull * 16 * 8 + 512ull * 2 * 4;

  int chunkT = 0;
  if (ws_size > aux) {
    long long ct = (long long)((ws_size - aux) / CHUNK_ROW_BYTES);
    if (ct > TT) ct = TT;
    ct &= ~1LL;  // even start for every chunk (list parity)
    if (ct >= 16) chunkT = (int)ct;
  }

  if (chunkT >= 16) {
    char* p = ws;
    float* i1ff = (float*)p;  p += (size_t)chunkT * CHUNK_ROW_BYTES;
    float* Wr2T = (float*)p;  p += TBL_BYTES;
    float* W2T  = (float*)p;  p += TBL_BYTES;
    float* stM1 = (float*)p;  p += ST_ARR_BYTES;
    float* stM2 = (float*)p;  p += ST_ARR_BYTES;
    u32* stSC1  = (u32*)p;    p += ST_ARR_BYTES;
    u32* stSC2  = (u32*)p;    p += ST_ARR_BYTES;
    u64* stW    = (u64*)p;    p += 512ull * 16 * 8;
    float* stMemo = (float*)p;

    hipLaunchKernelGGL(prep_weights, dim3((513 * 512 + 255) / 256), dim3(256), 0, stream,
                       W2, Wr2, Wr2T, W2T);
    for (int t0 = 0; t0 < TT; t0 += chunkT) {
      int len = (TT - t0 < chunkT) ? (TT - t0) : chunkT;
      hipLaunchKernelGGL(gemm_i1ff, dim3(BB, (len + T_TILE - 1) / T_TILE), dim3(128), 0,
                         stream, x, W1, i1ff, t0, len);
      hipLaunchKernelGGL(recur2, dim3(BB), dim3(512), 0, stream,
                         i1ff, Wr2T, W2T, W4, b1, b2, br2, b4,
                         Vth1, tau1, Vth2, tau2, tau_out, (float*)d_out,
                         stM1, stM2, stSC1, stSC2, stW, stMemo,
                         t0, len, (t0 == 0) ? 1 : 0, (t0 + len == TT) ? 1 : 0);
    }
  } else {
    float* Wr2T = (float*)ws;
    float* W2T  = (float*)(ws + TBL_BYTES);
    hipLaunchKernelGGL(prep_weights, dim3((513 * 512 + 255) / 256), dim3(256), 0, stream,
                       W2, Wr2, Wr2T, W2T);
    hipLaunchKernelGGL(recur_fb, dim3(BB), dim3(512), 0, stream,
                       x, W1, Wr2T, W2T, W4, b1, b2, br2, b4,
                       Vth1, tau1, Vth2, tau2, tau_out, (float*)d_out);
  }
}